// Round 1
// baseline (2714.634 us; speedup 1.0000x reference)
//
#include <hip/hip_runtime.h>
#include <cmath>

// Problem constants (from reference)
#define NN  5      // N_NODES
#define BB  4      // batch
#define CCH 256    // channels
#define HWD 1024   // H*W
#define THRESH_V 0.3f
#define EPS_V 1e-12f

// Tile config
#define CT 64      // channel rows per block
#define WT 64      // hw cols per block
#define KC 32      // k chunk
#define APAD 68    // padded LDS stride for A/W2 tiles (68*4B = 272B, 16B-aligned)

__global__ __launch_bounds__(256, 2)
void fub_main(const float* __restrict__ x, const float* __restrict__ wmat,
              const float* __restrict__ conv_w, const float* __restrict__ conv_b,
              float* __restrict__ out)
{
    __shared__ float Xs[NN][KC][WT];   // 40960 B
    __shared__ float As[KC][APAD];     //  8704 B
    __shared__ float W2s[KC][APAD];    //  8704 B

    const int tid = threadIdx.x;
    int bid = blockIdx.x;
    const int hwt = bid & 15; bid >>= 4;
    const int b   = bid & 3;  bid >>= 2;
    const int ct  = bid & 3;  bid >>= 2;
    const int i   = bid;               // 0..4

    const int c0  = ct * CT;
    const int hw0 = hwt * WT;

    const int tr = (tid >> 4) << 2;    // row base within tile: 0,4,...,60
    const int tc = (tid & 15) << 2;    // col base within tile: 0,4,...,60

    float acc[NN][4][4];               // per-j GEMM accumulators
    float accT[4][4];                  // term_i stream (W2[i] @ x[i])
#pragma unroll
    for (int j = 0; j < NN; ++j)
#pragma unroll
        for (int r = 0; r < 4; ++r)
#pragma unroll
            for (int c = 0; c < 4; ++c) acc[j][r][c] = 0.0f;
#pragma unroll
    for (int r = 0; r < 4; ++r)
#pragma unroll
        for (int c = 0; c < 4; ++c) accT[r][c] = 0.0f;

    for (int k0 = 0; k0 < CCH; k0 += KC) {
        // ---- stage x[j, b, k0:k0+KC, hw0:hw0+WT] for all j: 2560 float4 ----
#pragma unroll
        for (int it = 0; it < 10; ++it) {
            const int q   = tid + it * 256;
            const int pos = (q & 15) << 2;      // 0..60
            const int row = q >> 4;             // 0..159
            const int j   = row >> 5;           // 0..4
            const int kk  = row & 31;
            const float4 v = *(const float4*)(
                x + (size_t)((j * BB + b) * CCH + k0 + kk) * HWD + hw0 + pos);
            *(float4*)(&Xs[j][kk][pos]) = v;
        }
        // ---- stage A = W1+W2 and W2, transposed to [k][c] ----
#pragma unroll
        for (int it = 0; it < 2; ++it) {
            const int q  = tid + it * 256;
            const int r  = q >> 3;              // 0..63
            const int kq = (q & 7) << 2;        // 0,4,...,28
            const float* base =
                conv_w + (size_t)(i * CCH + c0 + r) * (2 * CCH) + k0 + kq;
            const float4 w1 = *(const float4*)(base);
            const float4 w2 = *(const float4*)(base + CCH);
            As[kq + 0][r] = w1.x + w2.x;
            As[kq + 1][r] = w1.y + w2.y;
            As[kq + 2][r] = w1.z + w2.z;
            As[kq + 3][r] = w1.w + w2.w;
            W2s[kq + 0][r] = w2.x;
            W2s[kq + 1][r] = w2.y;
            W2s[kq + 2][r] = w2.z;
            W2s[kq + 3][r] = w2.w;
        }
        __syncthreads();

        // ---- inner product over the chunk ----
#pragma unroll
        for (int kk = 0; kk < KC; ++kk) {
            const float4 av = *(const float4*)(&As[kk][tr]);
            const float4 wv = *(const float4*)(&W2s[kk][tr]);
            float4 xv[NN];
#pragma unroll
            for (int j = 0; j < NN; ++j)
                xv[j] = *(const float4*)(&Xs[j][kk][tc]);
            // x[i] column for the term_i stream (i is block-uniform)
            const float4 xvi = *(const float4*)(&Xs[i][kk][tc]);

            const float ar[4] = {av.x, av.y, av.z, av.w};
            const float wr[4] = {wv.x, wv.y, wv.z, wv.w};
#pragma unroll
            for (int j = 0; j < NN; ++j) {
                const float xc[4] = {xv[j].x, xv[j].y, xv[j].z, xv[j].w};
#pragma unroll
                for (int r = 0; r < 4; ++r)
#pragma unroll
                    for (int c = 0; c < 4; ++c)
                        acc[j][r][c] = fmaf(ar[r], xc[c], acc[j][r][c]);
            }
            const float xi[4] = {xvi.x, xvi.y, xvi.z, xvi.w};
#pragma unroll
            for (int r = 0; r < 4; ++r)
#pragma unroll
                for (int c = 0; c < 4; ++c)
                    accT[r][c] = fmaf(wr[r], xi[c], accT[r][c]);
        }
        __syncthreads();
    }

    // ---- epilogue: sigmoid / threshold / normalize over j / recombine ----
    float wrow[NN];
#pragma unroll
    for (int j = 0; j < NN; ++j) wrow[j] = wmat[i * NN + j];

#pragma unroll
    for (int r = 0; r < 4; ++r) {
        const int c = c0 + tr + r;
        const float bias = conv_b[i * CCH + c];

        float xjv[NN][4];
#pragma unroll
        for (int j = 0; j < NN; ++j) {
            const float4 v = *(const float4*)(
                x + (size_t)((j * BB + b) * CCH + c) * HWD + hw0 + tc);
            xjv[j][0] = v.x; xjv[j][1] = v.y; xjv[j][2] = v.z; xjv[j][3] = v.w;
        }

        float res[4];
#pragma unroll
        for (int cc = 0; cc < 4; ++cc) {
            float num = 0.0f, sq = 0.0f;
#pragma unroll
            for (int j = 0; j < NN; ++j) {
                const float dist = xjv[j][cc] - (acc[j][r][cc] + accT[r][cc] + bias);
                const float z = dist * wrow[j];
                float e = 1.0f / (1.0f + expf(-z));
                e = (e > THRESH_V) ? e : 0.0f;
                sq  = fmaf(e, e, sq);
                num = fmaf(e, xjv[j][cc], num);
            }
            const float nrm = sqrtf(sq);
            res[cc] = num / fmaxf(nrm, EPS_V);
        }
        *(float4*)(out + (size_t)((i * BB + b) * CCH + c) * HWD + hw0 + tc) =
            make_float4(res[0], res[1], res[2], res[3]);
    }
}

extern "C" void kernel_launch(void* const* d_in, const int* in_sizes, int n_in,
                              void* d_out, int out_size, void* d_ws, size_t ws_size,
                              hipStream_t stream) {
    const float* x      = (const float*)d_in[0];
    const float* w      = (const float*)d_in[1];
    const float* conv_w = (const float*)d_in[2];
    const float* conv_b = (const float*)d_in[3];
    float* out = (float*)d_out;

    // grid: i(5) * ct(4) * b(4) * hwt(16) = 1280 blocks
    dim3 grid(1280);
    dim3 block(256);
    fub_main<<<grid, block, 0, stream>>>(x, w, conv_w, conv_b, out);
}

// Round 2
// 361.502 us; speedup vs baseline: 7.5093x; 7.5093x over previous
//
#include <hip/hip_runtime.h>
#include <cmath>

// Problem constants (from reference)
#define NN  5      // N_NODES
#define BB  4      // batch
#define CCH 256    // channels
#define HWD 1024   // H*W
#define THRESH_V 0.3f
#define EPS_V 1e-12f

// Tile config: block = 384 threads = 6 waves; wave w<5 computes stream
// A[i]@x[w]; wave 5 computes W2[i]@x[i]. Each wave owns a 32x32 output tile
// (4x4 frag per lane -> only 16 accumulators/thread, no spill).
#define CT 32      // channel rows per block
#define WT 32      // hw cols per block
#define KC 32      // k chunk
#define APAD 36    // padded LDS row stride (floats) for A/W2 (odd-ish, 16B rows)
#define SPAD 36    // Es col stride (floats), rows 16B-aligned for float4 st/ld

// smem layout (floats):
//   staging phase: Xs[5][32][32] @0 (5120) | As[32][36] @5120 (1152) | W2s @6272 (1152)
//   epilogue:      Es[6][32][36] @0 (6912)   -- overlaid
#define SMEM_FLOATS 7424

__global__ __launch_bounds__(384, 4)
void fub_main(const float* __restrict__ x, const float* __restrict__ wmat,
              const float* __restrict__ conv_w, const float* __restrict__ conv_b,
              float* __restrict__ out)
{
    __shared__ __align__(16) float smem[SMEM_FLOATS];
    float* Xs  = smem;          // [5][KC][WT]
    float* As  = smem + 5120;   // [KC][APAD]
    float* W2s = smem + 6272;   // [KC][APAD]
    float* Es  = smem;          // [6][CT][SPAD] overlay (epilogue only)

    const int tid  = threadIdx.x;
    const int wv   = tid >> 6;        // 0..5 : stream id
    const int lane = tid & 63;

    int bid = blockIdx.x;
    const int hwt = bid & 31; bid >>= 5;   // 32 hw tiles
    const int b   = bid & 3;  bid >>= 2;   // 4 batches
    const int ct  = bid & 7;  bid >>= 3;   // 8 channel tiles
    const int i   = bid;                   // 0..4

    const int c0  = ct * CT;
    const int hw0 = hwt * WT;

    const int lr = (lane >> 3) << 2;  // frag row base 0,4,...,28
    const int lc = (lane & 7)  << 2;  // frag col base 0,4,...,28

    // stream w<5 multiplies A by x[w]; stream 5 multiplies W2 by x[i]
    const int jx = (wv < 5) ? wv : i;
    const float* M = (wv == 5) ? W2s : As;
    const float* Mb = M + lr;
    const float* Xb = Xs + jx * (KC * WT) + lc;

    float acc[4][4];
#pragma unroll
    for (int r = 0; r < 4; ++r)
#pragma unroll
        for (int c = 0; c < 4; ++c) acc[r][c] = 0.0f;

    for (int k0 = 0; k0 < CCH; k0 += KC) {
        // ---- stage: threads 0..319 load Xs (1280 float4), 320..383 load A/W2 ----
        if (tid < 320) {
#pragma unroll
            for (int it = 0; it < 4; ++it) {
                const int t   = tid + it * 320;       // 0..1279
                const int j   = t >> 8;               // 0..4
                const int rem = t & 255;
                const int kk  = rem >> 3;             // 0..31
                const int p4  = (rem & 7) << 2;       // 0..28
                const float4 v = *(const float4*)(
                    x + (size_t)((j * BB + b) * CCH + k0 + kk) * HWD + hw0 + p4);
                *(float4*)(Xs + j * (KC * WT) + kk * WT + p4) = v;
            }
        } else {
            const int u = tid - 320;                  // 0..63
#pragma unroll
            for (int it = 0; it < 4; ++it) {
                const int t  = u + (it << 6);         // 0..255
                const int r  = t >> 3;                // 0..31
                const int kq = (t & 7) << 2;          // 0..28
                const float* base =
                    conv_w + (size_t)(i * CCH + c0 + r) * (2 * CCH) + k0 + kq;
                const float4 w1 = *(const float4*)(base);
                const float4 w2 = *(const float4*)(base + CCH);
                As [(kq + 0) * APAD + r] = w1.x + w2.x;
                As [(kq + 1) * APAD + r] = w1.y + w2.y;
                As [(kq + 2) * APAD + r] = w1.z + w2.z;
                As [(kq + 3) * APAD + r] = w1.w + w2.w;
                W2s[(kq + 0) * APAD + r] = w2.x;
                W2s[(kq + 1) * APAD + r] = w2.y;
                W2s[(kq + 2) * APAD + r] = w2.z;
                W2s[(kq + 3) * APAD + r] = w2.w;
            }
        }
        __syncthreads();

        // ---- compute: each wave does its own stream's 32x32 tile ----
#pragma unroll
        for (int kk = 0; kk < KC; ++kk) {
            const float4 a  = *(const float4*)(Mb + kk * APAD);
            const float4 xv = *(const float4*)(Xb + kk * WT);
            const float ar[4] = {a.x, a.y, a.z, a.w};
            const float xc[4] = {xv.x, xv.y, xv.z, xv.w};
#pragma unroll
            for (int r = 0; r < 4; ++r)
#pragma unroll
                for (int c = 0; c < 4; ++c)
                    acc[r][c] = fmaf(ar[r], xc[c], acc[r][c]);
        }
        __syncthreads();
    }

    // ---- exchange streams through LDS (Es overlays staging buffers) ----
#pragma unroll
    for (int r = 0; r < 4; ++r) {
        *(float4*)(Es + wv * (CT * SPAD) + (lr + r) * SPAD + lc) =
            make_float4(acc[r][0], acc[r][1], acc[r][2], acc[r][3]);
    }
    __syncthreads();

    // ---- fused epilogue: threads 0..255, 4 elements each ----
    if (tid < 256) {
        const int row = tid >> 3;           // 0..31
        const int col = (tid & 7) << 2;     // 0..28
        const int c   = c0 + row;
        const float bias = conv_b[i * CCH + c];

        float wrow[NN];
#pragma unroll
        for (int j = 0; j < NN; ++j) wrow[j] = wmat[i * NN + j];

        const float4 T = *(const float4*)(Es + 5 * (CT * SPAD) + row * SPAD + col);
        const float Tv[4] = {T.x, T.y, T.z, T.w};

        float num[4] = {0.f, 0.f, 0.f, 0.f};
        float sq [4] = {0.f, 0.f, 0.f, 0.f};
#pragma unroll
        for (int j = 0; j < NN; ++j) {
            const float4 s  = *(const float4*)(Es + j * (CT * SPAD) + row * SPAD + col);
            const float4 xj = *(const float4*)(
                x + (size_t)((j * BB + b) * CCH + c) * HWD + hw0 + col);
            const float sv[4] = {s.x, s.y, s.z, s.w};
            const float xv[4] = {xj.x, xj.y, xj.z, xj.w};
#pragma unroll
            for (int cc = 0; cc < 4; ++cc) {
                const float target = sv[cc] + Tv[cc] + bias;
                const float dist   = xv[cc] - target;
                const float z      = dist * wrow[j];
                float e = 1.0f / (1.0f + expf(-z));
                e = (e > THRESH_V) ? e : 0.0f;
                sq[cc]  = fmaf(e, e, sq[cc]);
                num[cc] = fmaf(e, xv[cc], num[cc]);
            }
        }
        float res[4];
#pragma unroll
        for (int cc = 0; cc < 4; ++cc)
            res[cc] = num[cc] / fmaxf(sqrtf(sq[cc]), EPS_V);

        *(float4*)(out + (size_t)((i * BB + b) * CCH + c) * HWD + hw0 + col) =
            make_float4(res[0], res[1], res[2], res[3]);
    }
}

extern "C" void kernel_launch(void* const* d_in, const int* in_sizes, int n_in,
                              void* d_out, int out_size, void* d_ws, size_t ws_size,
                              hipStream_t stream) {
    const float* x      = (const float*)d_in[0];
    const float* w      = (const float*)d_in[1];
    const float* conv_w = (const float*)d_in[2];
    const float* conv_b = (const float*)d_in[3];
    float* out = (float*)d_out;

    // grid: i(5) * ct(8) * b(4) * hwt(32) = 5120 blocks of 384 threads
    dim3 grid(5120);
    dim3 block(384);
    fub_main<<<grid, block, 0, stream>>>(x, w, conv_w, conv_b, out);
}